// Round 1
// baseline (289.495 us; speedup 1.0000x reference)
//
#include <hip/hip_runtime.h>

// OU Euler-Maruyama: x_{i+1} = a*x_i + b_i,  a = 1 - gamma*dt (per-chain const),
// b_i = gamma*mu*dt + sigma*sqrt(dt)*eps_i.
// Parallelized via affine-map composition: per-lane 8-step local compose,
// 64-lane wave scan (shfl), sequential carry across tiles within one wave.
// One wave per (n,m) chain: 2048 waves total.

#define T_STEPS 20000
#define M_PATHS 64
#define CHUNK   8            // elements per lane per tile
#define TILE    (64 * CHUNK) // 512
#define NTILES  ((T_STEPS + TILE - 1) / TILE) // 40 (last tile partial: 32 elems)
#define DT      0.01f
#define SQRT_DT 0.1f

__global__ __launch_bounds__(256) void ou_scan_kernel(
    const float* __restrict__ theta,
    const float* __restrict__ noise,
    float* __restrict__ out)
{
    const int wave  = threadIdx.x >> 6;
    const int lane  = threadIdx.x & 63;
    const int chain = blockIdx.x * 4 + wave;      // 0 .. 2047
    const int n     = chain / M_PATHS;            // theta row

    const float gamma = theta[n * 4 + 0];
    const float mu    = theta[n * 4 + 1];
    const float sigma = theta[n * 4 + 2];
    float carry       = theta[n * 4 + 3];         // x_0

    const float a    = 1.0f - gamma * DT;
    const float gmdt = gamma * mu * DT;
    const float ssd  = sigma * SQRT_DT;
    const float a2 = a * a;
    const float a4 = a2 * a2;
    const float a8 = a4 * a4;

    const float* __restrict__ np_ = noise + (size_t)chain * T_STEPS;
    float* __restrict__       op_ = out   + (size_t)chain * T_STEPS;

    // ---- prefetch tile 0 ----
    float4 c0 = make_float4(0.f, 0.f, 0.f, 0.f);
    float4 c1 = make_float4(0.f, 0.f, 0.f, 0.f);
    {
        const int e0 = lane * CHUNK;
        if (e0 + CHUNK <= T_STEPS) {
            c0 = *(const float4*)(np_ + e0);
            c1 = *(const float4*)(np_ + e0 + 4);
        }
    }

    for (int tb = 0; tb < NTILES; ++tb) {
        // ---- prefetch next tile (issued before current tile's compute) ----
        float4 n0 = make_float4(0.f, 0.f, 0.f, 0.f);
        float4 n1 = make_float4(0.f, 0.f, 0.f, 0.f);
        const int ne0 = (tb + 1) * TILE + lane * CHUNK;
        if (tb + 1 < NTILES && ne0 + CHUNK <= T_STEPS) {
            n0 = *(const float4*)(np_ + ne0);
            n1 = *(const float4*)(np_ + ne0 + 4);
        }

        const int  base = tb * TILE + lane * CHUNK;
        const bool cact = (base + CHUNK <= T_STEPS);

        // b_j = gmdt + ssd * eps_j
        const float b0 = fmaf(ssd, c0.x, gmdt);
        const float b1 = fmaf(ssd, c0.y, gmdt);
        const float b2 = fmaf(ssd, c0.z, gmdt);
        const float b3 = fmaf(ssd, c0.w, gmdt);
        const float b4 = fmaf(ssd, c1.x, gmdt);
        const float b5 = fmaf(ssd, c1.y, gmdt);
        const float b6 = fmaf(ssd, c1.z, gmdt);
        const float b7 = fmaf(ssd, c1.w, gmdt);

        // local 8-step affine compose: x_out = a^8 * x_in + p
        float p = b0;
        p = fmaf(p, a, b1);
        p = fmaf(p, a, b2);
        p = fmaf(p, a, b3);
        p = fmaf(p, a, b4);
        p = fmaf(p, a, b5);
        p = fmaf(p, a, b6);
        p = fmaf(p, a, b7);

        float A = cact ? a8 : 1.0f;  // inactive lanes: identity map
        float B = cact ? p  : 0.0f;

        // inclusive wave scan of affine maps (lane order = time order)
        #pragma unroll
        for (int d = 1; d < 64; d <<= 1) {
            const float pA = __shfl_up(A, d);
            const float pB = __shfl_up(B, d);
            if (lane >= d) {
                B = fmaf(A, pB, B);   // cur ∘ prev : A*(pA x + pB) + B
                A = A * pA;
            }
        }

        // exclusive prefix for this lane
        float Aex = __shfl_up(A, 1);
        float Bex = __shfl_up(B, 1);
        if (lane == 0) { Aex = 1.0f; Bex = 0.0f; }
        float x = fmaf(Aex, carry, Bex);   // state entering this lane's chunk

        // carry across tiles: lane 63's inclusive map applied to carry
        const float A63 = __shfl(A, 63);
        const float B63 = __shfl(B, 63);
        carry = fmaf(A63, carry, B63);

        if (cact) {
            float4 o0, o1;
            x = fmaf(a, x, b0); o0.x = x;
            x = fmaf(a, x, b1); o0.y = x;
            x = fmaf(a, x, b2); o0.z = x;
            x = fmaf(a, x, b3); o0.w = x;
            x = fmaf(a, x, b4); o1.x = x;
            x = fmaf(a, x, b5); o1.y = x;
            x = fmaf(a, x, b6); o1.z = x;
            x = fmaf(a, x, b7); o1.w = x;
            *(float4*)(op_ + base)     = o0;
            *(float4*)(op_ + base + 4) = o1;
        }

        c0 = n0;
        c1 = n1;
    }
}

extern "C" void kernel_launch(void* const* d_in, const int* in_sizes, int n_in,
                              void* d_out, int out_size, void* d_ws, size_t ws_size,
                              hipStream_t stream) {
    const float* theta = (const float*)d_in[0];
    const float* noise = (const float*)d_in[1];
    float* out = (float*)d_out;

    const int chains = in_sizes[1] / T_STEPS;   // 2048
    const int blocks = chains / 4;              // 4 waves (chains) per 256-thr block
    ou_scan_kernel<<<blocks, 256, 0, stream>>>(theta, noise, out);
}